// Round 23
// baseline (84.315 us; speedup 1.0000x reference)
//
#include <hip/hip_runtime.h>
#include <hip/hip_bf16.h>

using bf16x8 = __attribute__((ext_vector_type(8))) short;
using f32x4  = __attribute__((ext_vector_type(4))) float;
using f32x16 = __attribute__((ext_vector_type(16))) float;
using u32x4  = __attribute__((ext_vector_type(4))) unsigned;

__device__ __forceinline__ short f2bf(float f) {
  union { float f; unsigned u; } v; v.f = f;
  unsigned r = (v.u + 0x7FFFu + ((v.u >> 16) & 1u)) >> 16;
  return (short)(unsigned short)r;
}

__device__ __forceinline__ unsigned cvtpk(float lo, float hi) {
  unsigned r;
  asm("v_cvt_pk_bf16_f32 %0, %1, %2" : "=v"(r) : "v"(lo), "v"(hi));
  return r;
}

__device__ __forceinline__ void plswap(unsigned &a, unsigned &b) {
  asm("v_permlane32_swap_b32 %0, %1" : "+v"(a), "+v"(b));
}

#define GLLDS(gp, lp) __builtin_amdgcn_global_load_lds(                        \
    (const __attribute__((address_space(1))) void*)(gp),                       \
    (__attribute__((address_space(3))) void*)(lp), 16, 0, 0)

// ---------------- fused fp32 -> bf16 conversion: x and w_qkv ---------------
__global__ __launch_bounds__(256)
void cvt_xw(const float* __restrict__ x, const float* __restrict__ wq,
            short* __restrict__ xb, short* __restrict__ wb)
{
  const int blk = blockIdx.x;
  const float* src;
  short* dst;
  int i;
  if (blk < 2048) { src = x;  dst = xb; i = blk * 256 + threadIdx.x; }
  else            { src = wq; dst = wb; i = (blk - 2048) * 256 + threadIdx.x; }
  float4 lo = *(const float4*)(src + (size_t)i * 8);
  float4 hi = *(const float4*)(src + (size_t)i * 8 + 4);
  uint4 r;
  r.x = cvtpk(lo.x, lo.y);
  r.y = cvtpk(lo.z, lo.w);
  r.z = cvtpk(hi.x, hi.y);
  r.w = cvtpk(hi.z, hi.w);
  *(uint4*)(dst + (size_t)i * 8) = r;
}

// ---------------- small fp32 -> bf16 conversion (w_out) --------------------
__global__ __launch_bounds__(256)
void cvt_f32_bf16(const float* __restrict__ in, short* __restrict__ out, int n8)
{
  int i = blockIdx.x * 256 + threadIdx.x;
  if (i >= n8) return;
  float4 lo = *(const float4*)(in + (size_t)i * 8);
  float4 hi = *(const float4*)(in + (size_t)i * 8 + 4);
  uint4 r;
  r.x = cvtpk(lo.x, lo.y);
  r.y = cvtpk(lo.z, lo.w);
  r.z = cvtpk(hi.x, hi.y);
  r.w = cvtpk(hi.z, hi.w);
  *(uint4*)(out + (size_t)i * 8) = r;
}

// ---------------- QKV projection: BK=64, XCD-chunked swizzle, 3 blk/CU -----
__global__ __launch_bounds__(256, 3)
void gemm_qkv(const short* __restrict__ A, const short* __restrict__ B,
              short* __restrict__ outQ, short* __restrict__ outK,
              short* __restrict__ outVt, const float* __restrict__ temp)
{
  __shared__ short As[128 * 64];
  __shared__ short Bs[128 * 64];
  const int Kd = 512;
  const int tid  = threadIdx.x;
  const int lane = tid & 63;
  const int w    = tid >> 6;
  const int wr   = w >> 1, wc = w & 1;
  const int fr   = lane & 15, fq = lane >> 4;
  const int g  = blockIdx.x;
  const int xcd = g & 7, gi = g >> 3;
  const int bm = xcd * 8 + gi / 12;
  const int bn = gi % 12;
  const int rowA = bm * 128, rowB = bn * 128;

  const int lrow8   = lane >> 3;
  const int lchunk8 = ((lane & 7) ^ lrow8) * 8;
  const short* gA0 = A + (size_t)(rowA + w * 8 + lrow8) * Kd + lchunk8;
  const short* gB0 = B + (size_t)(rowB + w * 8 + lrow8) * Kd + lchunk8;
  char* lA0 = (char*)As + w * 1024;
  char* lB0 = (char*)Bs + w * 1024;
  const int rx7 = fr & 7;

  f32x4 acc[4][4];
  #pragma unroll
  for (int m = 0; m < 4; ++m)
    #pragma unroll
    for (int n = 0; n < 4; ++n) acc[m][n] = (f32x4){0.f, 0.f, 0.f, 0.f};

  for (int k0 = 0; k0 < Kd; k0 += 64) {
    #pragma unroll
    for (int i = 0; i < 4; ++i) {
      GLLDS(gA0 + k0 + i * 32 * Kd, lA0 + i * 4096);
      GLLDS(gB0 + k0 + i * 32 * Kd, lB0 + i * 4096);
    }
    __syncthreads();
    #pragma unroll
    for (int s = 0; s < 2; ++s) {
      bf16x8 afr[4], bfr[4];
      #pragma unroll
      for (int m = 0; m < 4; ++m)
        afr[m] = *(const bf16x8*)((char*)As + (wr*64 + m*16 + fr) * 128
                                  + (((s*4 + fq) ^ rx7) << 4));
      #pragma unroll
      for (int n = 0; n < 4; ++n)
        bfr[n] = *(const bf16x8*)((char*)Bs + (wc*64 + n*16 + fr) * 128
                                  + (((s*4 + fq) ^ rx7) << 4));
      #pragma unroll
      for (int m = 0; m < 4; ++m)
        #pragma unroll
        for (int n = 0; n < 4; ++n)
          acc[m][n] = __builtin_amdgcn_mfma_f32_16x16x32_bf16(afr[m], bfr[n], acc[m][n], 0, 0, 0);
    }
    __syncthreads();
  }

  const int gc0   = rowB + wc*64;
  const int slice = gc0 >> 6;
  const int t3    = slice >> 3;
  const int h     = slice & 7;
  if (t3 < 2) {
    float scl[4][4];
    const float tval = (t3 == 0) ? temp[h] * 1.44269504088896f : 1.0f;
    #pragma unroll
    for (int m = 0; m < 4; ++m) {
      #pragma unroll
      for (int r = 0; r < 4; ++r) {
        float ss = 0.f;
        #pragma unroll
        for (int n = 0; n < 4; ++n) ss += acc[m][n][r] * acc[m][n][r];
        #pragma unroll
        for (int off = 1; off < 16; off <<= 1) ss += __shfl_xor(ss, off);
        scl[m][r] = tval / fmaxf(sqrtf(ss), 1e-12f);
      }
    }
    short* dst = (t3 == 0) ? outQ : outK;
    #pragma unroll
    for (int m = 0; m < 4; ++m) {
      #pragma unroll
      for (int r = 0; r < 4; ++r) {
        int rg = rowA + wr*64 + m*16 + fq*4 + r;
        int b = rg >> 11, nn = rg & 2047;
        size_t rowoff = ((size_t)(b*8 + h) * 2048 + nn) * 64;
        #pragma unroll
        for (int n = 0; n < 4; ++n)
          dst[rowoff + n*16 + fr] = f2bf(acc[m][n][r] * scl[m][r]);
      }
    }
  } else {
    // V: tokens (fq*4 + r, r=0..3) are consecutive -> pack into 8B stores.
    #pragma unroll
    for (int m = 0; m < 4; ++m) {
      int rg0 = rowA + wr*64 + m*16 + fq*4;
      int b = rg0 >> 11, nn0 = rg0 & 2047;
      size_t dbase = (size_t)(b*8 + h) * 64;
      #pragma unroll
      for (int n = 0; n < 4; ++n) {
        unsigned lo = cvtpk(acc[m][n][0], acc[m][n][1]);
        unsigned hi = cvtpk(acc[m][n][2], acc[m][n][3]);
        *(uint2*)(outVt + (dbase + n*16 + fr) * 2048 + nn0) = make_uint2(lo, hi);
      }
    }
  }
}

// ---------------- output projection: 128x64 tile, XCD-chunked swizzle ------
__global__ __launch_bounds__(256, 2)
void gemm_out(const short* __restrict__ A, const short* __restrict__ B,
              float* __restrict__ outC)
{
  __shared__ short As[128 * 64];
  __shared__ short Bs[64 * 64];
  const int Kd = 512, N = 512;
  const int tid  = threadIdx.x;
  const int lane = tid & 63;
  const int w    = tid >> 6;
  const int fr   = lane & 15, fq = lane >> 4;
  const int g  = blockIdx.x;
  const int xcd = g & 7, gi = g >> 3;
  const int bm = xcd * 8 + gi / 8;
  const int bn = gi % 8;
  const int rowA = bm * 128, rowB = bn * 64;

  const int lrow8   = lane >> 3;
  const int lchunk8 = ((lane & 7) ^ lrow8) * 8;
  const short* gA0 = A + (size_t)(rowA + w * 8 + lrow8) * Kd + lchunk8;
  const short* gB0 = B + (size_t)(rowB + w * 8 + lrow8) * Kd + lchunk8;
  char* lA0 = (char*)As + w * 1024;
  char* lB0 = (char*)Bs + w * 1024;
  const int rx7 = fr & 7;

  f32x4 acc[2][4];
  #pragma unroll
  for (int m = 0; m < 2; ++m)
    #pragma unroll
    for (int n = 0; n < 4; ++n) acc[m][n] = (f32x4){0.f, 0.f, 0.f, 0.f};

  for (int k0 = 0; k0 < Kd; k0 += 64) {
    #pragma unroll
    for (int i = 0; i < 4; ++i)
      GLLDS(gA0 + k0 + i * 32 * Kd, lA0 + i * 4096);
    #pragma unroll
    for (int j = 0; j < 2; ++j)
      GLLDS(gB0 + k0 + j * 32 * Kd, lB0 + j * 4096);
    __syncthreads();
    #pragma unroll
    for (int s = 0; s < 2; ++s) {
      bf16x8 afr[2], bfr[4];
      #pragma unroll
      for (int m = 0; m < 2; ++m)
        afr[m] = *(const bf16x8*)((char*)As + (w*32 + m*16 + fr) * 128
                                  + (((s*4 + fq) ^ rx7) << 4));
      #pragma unroll
      for (int n = 0; n < 4; ++n)
        bfr[n] = *(const bf16x8*)((char*)Bs + (n*16 + fr) * 128
                                  + (((s*4 + fq) ^ rx7) << 4));
      #pragma unroll
      for (int m = 0; m < 2; ++m)
        #pragma unroll
        for (int n = 0; n < 4; ++n)
          acc[m][n] = __builtin_amdgcn_mfma_f32_16x16x32_bf16(afr[m], bfr[n], acc[m][n], 0, 0, 0);
    }
    __syncthreads();
  }

  #pragma unroll
  for (int m = 0; m < 2; ++m) {
    int r0 = rowA + w*32 + m*16 + fq*4;
    #pragma unroll
    for (int n = 0; n < 4; ++n) {
      int c = rowB + n*16 + fr;
      #pragma unroll
      for (int r = 0; r < 4; ++r)
        outC[(size_t)(r0 + r) * N + c] = acc[m][n][r];
    }
  }
}

// ---------------- flash attention v11: v9 + split PV accumulators ----------
// KVBLK=128, ds_write staging (r20/21-proven). PV accumulation split into
// two persistent partials per td (kj 0-3 -> o, kj 4-7 -> o2): independent
// MFMA dependency chains per wave 2 -> 4, hiding accumulate latency.
// Exact: disjoint k-ranges summed once in the epilogue.
__global__ __launch_bounds__(256, 2)
void attn_fwd(const short* __restrict__ Q, const short* __restrict__ Kt,
              const short* __restrict__ Vt, short* __restrict__ AO,
              const float* __restrict__ temp)
{
  __shared__ short Kl[2][128 * 64];
  __shared__ short Vl[2][64 * 128];
  __shared__ float Ls[4][32];
  const int tid  = threadIdx.x;
  const int lane = tid & 63;
  const int w    = tid >> 6;
  const int l31  = lane & 31;
  const int hi   = lane >> 5;
  const int bh = blockIdx.x;          // XCD = bh%8
  const int qt = blockIdx.y;
  const int b = bh >> 3, h = bh & 7;
  const size_t base  = (size_t)bh * 2048 * 64;
  const size_t vbase = (size_t)bh * 64 * 2048;
  const int q0 = qt * 128 + w * 32;

  const short* kp = Kt + base;
  const short* vp = Vt + vbase;

  const int srowK = tid >> 3;
  const int scol8 = (tid & 7) * 8;
  const int scolB = (tid & 7) * 16;
  const int sxorK = (srowK & 7) << 4;
  const int vr0   = tid >> 4;
  const int vcB   = (tid & 15) * 16;
  const int vc8   = (tid & 15) * 8;
  const int sxorV = (vr0 & 7) << 4;
  const int kswz  = (l31 & 7) << 4;

  bf16x8 stK[4], stV[4];
  #define LOAD_TILE(T)                                                              \
    do { int kt_ = (T) * 128;                                                       \
      _Pragma("unroll")                                                             \
      for (int i_ = 0; i_ < 4; ++i_)                                                \
        stK[i_] = *(const bf16x8*)(kp + (size_t)(kt_ + i_*32 + srowK) * 64 + scol8);\
      _Pragma("unroll")                                                             \
      for (int i_ = 0; i_ < 4; ++i_)                                                \
        stV[i_] = *(const bf16x8*)(vp + (size_t)(i_*16 + vr0) * 2048 + kt_ + vc8);  \
    } while (0)
  #define WRITE_TILE(P_)                                                            \
    do {                                                                            \
      _Pragma("unroll")                                                             \
      for (int i_ = 0; i_ < 4; ++i_)                                                \
        *(bf16x8*)((char*)Kl[P_] + (i_*32 + srowK) * 128 + (scolB ^ sxorK)) = stK[i_];\
      _Pragma("unroll")                                                             \
      for (int i_ = 0; i_ < 4; ++i_)                                                \
        *(bf16x8*)((char*)Vl[P_] + (i_*16 + vr0) * 256 + (vcB ^ sxorV)) = stV[i_];  \
    } while (0)

  bf16x8 bq[4];
  #pragma unroll
  for (int dj = 0; dj < 4; ++dj)
    bq[dj] = *(const bf16x8*)(Q + base + (size_t)(q0 + l31) * 64 + dj*16 + hi*8);

  const float Mh = fabsf(temp[h]) * 1.44269504088896f;
  f32x16 cinit;
  #pragma unroll
  for (int r = 0; r < 16; ++r) cinit[r] = -Mh;

  f32x16 o[2], o2[2];
  #pragma unroll
  for (int td = 0; td < 2; ++td)
    #pragma unroll
    for (int r = 0; r < 16; ++r) { o[td][r] = 0.f; o2[td][r] = 0.f; }
  float lp = 0.f;

  LOAD_TILE(0); WRITE_TILE(0);
  LOAD_TILE(1); WRITE_TILE(1);
  LOAD_TILE(2);
  __syncthreads();

  for (int t = 0; t < 16; ++t) {
    const int p = t & 1;
    const char* kl = (const char*)Kl[p];
    const char* vl = (const char*)Vl[p];

    f32x16 s[4];
    #pragma unroll
    for (int tk = 0; tk < 4; ++tk) {
      f32x16 z = cinit;
      #pragma unroll
      for (int dj = 0; dj < 4; ++dj) {
        bf16x8 ak = *(const bf16x8*)(kl + (tk*32 + l31) * 128 + ((dj*32 + hi*16) ^ kswz));
        z = __builtin_amdgcn_mfma_f32_32x32x16_bf16(ak, bq[dj], z, 0, 0, 0);
      }
      s[tk] = z;
    }
    #pragma unroll
    for (int tk = 0; tk < 4; ++tk)
      #pragma unroll
      for (int r = 0; r < 16; ++r) {
        float pv = __builtin_amdgcn_exp2f(s[tk][r]);
        s[tk][r] = pv;
        lp += pv;
      }
    bf16x8 pa[8];
    #pragma unroll
    for (int tk = 0; tk < 4; ++tk)
      #pragma unroll
      for (int j = 0; j < 2; ++j) {
        unsigned w0 = cvtpk(s[tk][8*j+0], s[tk][8*j+1]);
        unsigned w2 = cvtpk(s[tk][8*j+4], s[tk][8*j+5]);
        unsigned w1 = cvtpk(s[tk][8*j+2], s[tk][8*j+3]);
        unsigned w3 = cvtpk(s[tk][8*j+6], s[tk][8*j+7]);
        plswap(w0, w2);
        plswap(w1, w3);
        u32x4 pw = {w0, w1, w2, w3};
        pa[tk*2 + j] = __builtin_bit_cast(bf16x8, pw);
      }
    // PV: 4 independent accumulation chains (td x {kj0-3, kj4-7})
    #pragma unroll
    for (int td = 0; td < 2; ++td) {
      f32x16 accA = o[td];
      f32x16 accB = o2[td];
      #pragma unroll
      for (int kj = 0; kj < 4; ++kj) {
        bf16x8 bvA = *(const bf16x8*)(vl + (td*32 + l31) * 256 + (((kj    )*32 + hi*16) ^ kswz));
        bf16x8 bvB = *(const bf16x8*)(vl + (td*32 + l31) * 256 + (((kj + 4)*32 + hi*16) ^ kswz));
        accA = __builtin_amdgcn_mfma_f32_32x32x16_bf16(pa[kj],     bvA, accA, 0, 0, 0);
        accB = __builtin_amdgcn_mfma_f32_32x32x16_bf16(pa[kj + 4], bvB, accB, 0, 0, 0);
      }
      o[td]  = accA;
      o2[td] = accB;
    }

    if (t < 15) {
      __syncthreads();
      if (t < 14) {
        WRITE_TILE(p);
        if (t < 13) LOAD_TILE(t + 3);
      }
    }
  }
  #undef LOAD_TILE
  #undef WRITE_TILE

  lp += __shfl_xor(lp, 32);
  if (hi == 0) Ls[w][l31] = 1.0f / lp;
  #pragma unroll
  for (int td = 0; td < 2; ++td)
    #pragma unroll
    for (int r = 0; r < 16; ++r) {
      int qr = (r & 3) + 8 * (r >> 2) + 4 * hi;
      float li = Ls[w][qr];
      int row = b * 2048 + q0 + qr;
      int col = h * 64 + td * 32 + l31;
      AO[(size_t)row * 512 + col] = f2bf((o[td][r] + o2[td][r]) * li);
    }
}

extern "C" void kernel_launch(void* const* d_in, const int* in_sizes, int n_in,
                              void* d_out, int out_size, void* d_ws, size_t ws_size,
                              hipStream_t stream)
{
  const float* x     = (const float*)d_in[0];   // [4,2048,512] fp32
  const float* w_qkv = (const float*)d_in[1];   // [1536,512]  fp32
  const float* w_out = (const float*)d_in[2];   // [512,512]   fp32
  const float* temp  = (const float*)d_in[3];   // [8,1,1]     fp32
  float* out = (float*)d_out;
  short* ws  = (short*)d_ws;

  const size_t NQ = (size_t)4 * 8 * 2048 * 64;  // 4194304
  short* Qb   = ws;            // bf16 [b,h,n,64]
  short* Kb   = ws + NQ;       // bf16 [b,h,n,64]
  short* Vtb  = ws + 2 * NQ;   // bf16 [b,h,64,n]
  short* AO16 = ws + 3 * NQ;   // bf16 [8192,512] attention out (after attn)
  short* xb   = ws + 4 * NQ;   // bf16 x (live during gemm_qkv)
  short* wb   = AO16;          // bf16 w_qkv — dead before attn writes AO
  short* wob  = xb;            // bf16 w_out — cvt'd after gemm_qkv (xb dead)

  cvt_xw<<<dim3(2432), 256, 0, stream>>>(x, w_qkv, xb, wb);
  gemm_qkv<<<dim3(768), 256, 0, stream>>>(xb, wb, Qb, Kb, Vtb, temp);
  cvt_f32_bf16<<<dim3(128), 256, 0, stream>>>(w_out, wob, 32768);
  attn_fwd<<<dim3(32, 16), 256, 0, stream>>>(Qb, Kb, Vtb, AO16, temp);
  gemm_out<<<dim3(512), 256, 0, stream>>>(AO16, wob, out);
}

// Round 24
// 81.914 us; speedup vs baseline: 1.0293x; 1.0293x over previous
//
#include <hip/hip_runtime.h>
#include <hip/hip_bf16.h>

using bf16x8 = __attribute__((ext_vector_type(8))) short;
using f32x4  = __attribute__((ext_vector_type(4))) float;
using f32x16 = __attribute__((ext_vector_type(16))) float;
using u32x4  = __attribute__((ext_vector_type(4))) unsigned;

__device__ __forceinline__ short f2bf(float f) {
  union { float f; unsigned u; } v; v.f = f;
  unsigned r = (v.u + 0x7FFFu + ((v.u >> 16) & 1u)) >> 16;
  return (short)(unsigned short)r;
}

__device__ __forceinline__ unsigned cvtpk(float lo, float hi) {
  unsigned r;
  asm("v_cvt_pk_bf16_f32 %0, %1, %2" : "=v"(r) : "v"(lo), "v"(hi));
  return r;
}

__device__ __forceinline__ void plswap(unsigned &a, unsigned &b) {
  asm("v_permlane32_swap_b32 %0, %1" : "+v"(a), "+v"(b));
}

#define GLLDS(gp, lp) __builtin_amdgcn_global_load_lds(                        \
    (const __attribute__((address_space(1))) void*)(gp),                       \
    (__attribute__((address_space(3))) void*)(lp), 16, 0, 0)

// ---------------- fused fp32 -> bf16 conversion: x and w_qkv ---------------
__global__ __launch_bounds__(256)
void cvt_xw(const float* __restrict__ x, const float* __restrict__ wq,
            short* __restrict__ xb, short* __restrict__ wb)
{
  const int blk = blockIdx.x;
  const float* src;
  short* dst;
  int i;
  if (blk < 2048) { src = x;  dst = xb; i = blk * 256 + threadIdx.x; }
  else            { src = wq; dst = wb; i = (blk - 2048) * 256 + threadIdx.x; }
  float4 lo = *(const float4*)(src + (size_t)i * 8);
  float4 hi = *(const float4*)(src + (size_t)i * 8 + 4);
  uint4 r;
  r.x = cvtpk(lo.x, lo.y);
  r.y = cvtpk(lo.z, lo.w);
  r.z = cvtpk(hi.x, hi.y);
  r.w = cvtpk(hi.z, hi.w);
  *(uint4*)(dst + (size_t)i * 8) = r;
}

// ---------------- small fp32 -> bf16 conversion (w_out) --------------------
__global__ __launch_bounds__(256)
void cvt_f32_bf16(const float* __restrict__ in, short* __restrict__ out, int n8)
{
  int i = blockIdx.x * 256 + threadIdx.x;
  if (i >= n8) return;
  float4 lo = *(const float4*)(in + (size_t)i * 8);
  float4 hi = *(const float4*)(in + (size_t)i * 8 + 4);
  uint4 r;
  r.x = cvtpk(lo.x, lo.y);
  r.y = cvtpk(lo.z, lo.w);
  r.z = cvtpk(hi.x, hi.y);
  r.w = cvtpk(hi.z, hi.w);
  *(uint4*)(out + (size_t)i * 8) = r;
}

// ---------------- QKV projection: BK=64, XCD-chunked swizzle, 3 blk/CU -----
__global__ __launch_bounds__(256, 3)
void gemm_qkv(const short* __restrict__ A, const short* __restrict__ B,
              short* __restrict__ outQ, short* __restrict__ outK,
              short* __restrict__ outVt, const float* __restrict__ temp)
{
  __shared__ short As[128 * 64];
  __shared__ short Bs[128 * 64];
  const int Kd = 512;
  const int tid  = threadIdx.x;
  const int lane = tid & 63;
  const int w    = tid >> 6;
  const int wr   = w >> 1, wc = w & 1;
  const int fr   = lane & 15, fq = lane >> 4;
  const int g  = blockIdx.x;
  const int xcd = g & 7, gi = g >> 3;
  const int bm = xcd * 8 + gi / 12;
  const int bn = gi % 12;
  const int rowA = bm * 128, rowB = bn * 128;

  const int lrow8   = lane >> 3;
  const int lchunk8 = ((lane & 7) ^ lrow8) * 8;
  const short* gA0 = A + (size_t)(rowA + w * 8 + lrow8) * Kd + lchunk8;
  const short* gB0 = B + (size_t)(rowB + w * 8 + lrow8) * Kd + lchunk8;
  char* lA0 = (char*)As + w * 1024;
  char* lB0 = (char*)Bs + w * 1024;
  const int rx7 = fr & 7;

  f32x4 acc[4][4];
  #pragma unroll
  for (int m = 0; m < 4; ++m)
    #pragma unroll
    for (int n = 0; n < 4; ++n) acc[m][n] = (f32x4){0.f, 0.f, 0.f, 0.f};

  for (int k0 = 0; k0 < Kd; k0 += 64) {
    #pragma unroll
    for (int i = 0; i < 4; ++i) {
      GLLDS(gA0 + k0 + i * 32 * Kd, lA0 + i * 4096);
      GLLDS(gB0 + k0 + i * 32 * Kd, lB0 + i * 4096);
    }
    __syncthreads();
    #pragma unroll
    for (int s = 0; s < 2; ++s) {
      bf16x8 afr[4], bfr[4];
      #pragma unroll
      for (int m = 0; m < 4; ++m)
        afr[m] = *(const bf16x8*)((char*)As + (wr*64 + m*16 + fr) * 128
                                  + (((s*4 + fq) ^ rx7) << 4));
      #pragma unroll
      for (int n = 0; n < 4; ++n)
        bfr[n] = *(const bf16x8*)((char*)Bs + (wc*64 + n*16 + fr) * 128
                                  + (((s*4 + fq) ^ rx7) << 4));
      #pragma unroll
      for (int m = 0; m < 4; ++m)
        #pragma unroll
        for (int n = 0; n < 4; ++n)
          acc[m][n] = __builtin_amdgcn_mfma_f32_16x16x32_bf16(afr[m], bfr[n], acc[m][n], 0, 0, 0);
    }
    __syncthreads();
  }

  const int gc0   = rowB + wc*64;
  const int slice = gc0 >> 6;
  const int t3    = slice >> 3;
  const int h     = slice & 7;
  if (t3 < 2) {
    float scl[4][4];
    const float tval = (t3 == 0) ? temp[h] * 1.44269504088896f : 1.0f;
    #pragma unroll
    for (int m = 0; m < 4; ++m) {
      #pragma unroll
      for (int r = 0; r < 4; ++r) {
        float ss = 0.f;
        #pragma unroll
        for (int n = 0; n < 4; ++n) ss += acc[m][n][r] * acc[m][n][r];
        #pragma unroll
        for (int off = 1; off < 16; off <<= 1) ss += __shfl_xor(ss, off);
        scl[m][r] = tval / fmaxf(sqrtf(ss), 1e-12f);
      }
    }
    short* dst = (t3 == 0) ? outQ : outK;
    #pragma unroll
    for (int m = 0; m < 4; ++m) {
      #pragma unroll
      for (int r = 0; r < 4; ++r) {
        int rg = rowA + wr*64 + m*16 + fq*4 + r;
        int b = rg >> 11, nn = rg & 2047;
        size_t rowoff = ((size_t)(b*8 + h) * 2048 + nn) * 64;
        #pragma unroll
        for (int n = 0; n < 4; ++n)
          dst[rowoff + n*16 + fr] = f2bf(acc[m][n][r] * scl[m][r]);
      }
    }
  } else {
    #pragma unroll
    for (int m = 0; m < 4; ++m) {
      #pragma unroll
      for (int r = 0; r < 4; ++r) {
        int rg = rowA + wr*64 + m*16 + fq*4 + r;
        int b = rg >> 11, nn = rg & 2047;
        #pragma unroll
        for (int n = 0; n < 4; ++n)
          outVt[((size_t)(b*8 + h) * 64 + n*16 + fr) * 2048 + nn] = f2bf(acc[m][n][r]);
      }
    }
  }
}

// ---------------- output projection: 128x64 tile, XCD-chunked swizzle ------
__global__ __launch_bounds__(256, 2)
void gemm_out(const short* __restrict__ A, const short* __restrict__ B,
              float* __restrict__ outC)
{
  __shared__ short As[128 * 64];
  __shared__ short Bs[64 * 64];
  const int Kd = 512, N = 512;
  const int tid  = threadIdx.x;
  const int lane = tid & 63;
  const int w    = tid >> 6;
  const int fr   = lane & 15, fq = lane >> 4;
  const int g  = blockIdx.x;
  const int xcd = g & 7, gi = g >> 3;
  const int bm = xcd * 8 + gi / 8;
  const int bn = gi % 8;
  const int rowA = bm * 128, rowB = bn * 64;

  const int lrow8   = lane >> 3;
  const int lchunk8 = ((lane & 7) ^ lrow8) * 8;
  const short* gA0 = A + (size_t)(rowA + w * 8 + lrow8) * Kd + lchunk8;
  const short* gB0 = B + (size_t)(rowB + w * 8 + lrow8) * Kd + lchunk8;
  char* lA0 = (char*)As + w * 1024;
  char* lB0 = (char*)Bs + w * 1024;
  const int rx7 = fr & 7;

  f32x4 acc[2][4];
  #pragma unroll
  for (int m = 0; m < 2; ++m)
    #pragma unroll
    for (int n = 0; n < 4; ++n) acc[m][n] = (f32x4){0.f, 0.f, 0.f, 0.f};

  for (int k0 = 0; k0 < Kd; k0 += 64) {
    #pragma unroll
    for (int i = 0; i < 4; ++i)
      GLLDS(gA0 + k0 + i * 32 * Kd, lA0 + i * 4096);
    #pragma unroll
    for (int j = 0; j < 2; ++j)
      GLLDS(gB0 + k0 + j * 32 * Kd, lB0 + j * 4096);
    __syncthreads();
    #pragma unroll
    for (int s = 0; s < 2; ++s) {
      bf16x8 afr[2], bfr[4];
      #pragma unroll
      for (int m = 0; m < 2; ++m)
        afr[m] = *(const bf16x8*)((char*)As + (w*32 + m*16 + fr) * 128
                                  + (((s*4 + fq) ^ rx7) << 4));
      #pragma unroll
      for (int n = 0; n < 4; ++n)
        bfr[n] = *(const bf16x8*)((char*)Bs + (n*16 + fr) * 128
                                  + (((s*4 + fq) ^ rx7) << 4));
      #pragma unroll
      for (int m = 0; m < 2; ++m)
        #pragma unroll
        for (int n = 0; n < 4; ++n)
          acc[m][n] = __builtin_amdgcn_mfma_f32_16x16x32_bf16(afr[m], bfr[n], acc[m][n], 0, 0, 0);
    }
    __syncthreads();
  }

  #pragma unroll
  for (int m = 0; m < 2; ++m) {
    int r0 = rowA + w*32 + m*16 + fq*4;
    #pragma unroll
    for (int n = 0; n < 4; ++n) {
      int c = rowB + n*16 + fr;
      #pragma unroll
      for (int r = 0; r < 4; ++r)
        outC[(size_t)(r0 + r) * N + c] = acc[m][n][r];
    }
  }
}

// ---------------- flash attention v9 (session best, 45.4us) ----------------
__global__ __launch_bounds__(256, 2)
void attn_fwd(const short* __restrict__ Q, const short* __restrict__ Kt,
              const short* __restrict__ Vt, short* __restrict__ AO,
              const float* __restrict__ temp)
{
  __shared__ short Kl[2][128 * 64];
  __shared__ short Vl[2][64 * 128];
  __shared__ float Ls[4][32];
  const int tid  = threadIdx.x;
  const int lane = tid & 63;
  const int w    = tid >> 6;
  const int l31  = lane & 31;
  const int hi   = lane >> 5;
  const int bh = blockIdx.x;          // XCD = bh%8
  const int qt = blockIdx.y;
  const int b = bh >> 3, h = bh & 7;
  const size_t base  = (size_t)bh * 2048 * 64;
  const size_t vbase = (size_t)bh * 64 * 2048;
  const int q0 = qt * 128 + w * 32;

  const short* kp = Kt + base;
  const short* vp = Vt + vbase;

  const int srowK = tid >> 3;
  const int scol8 = (tid & 7) * 8;
  const int scolB = (tid & 7) * 16;
  const int sxorK = (srowK & 7) << 4;
  const int vr0   = tid >> 4;
  const int vcB   = (tid & 15) * 16;
  const int vc8   = (tid & 15) * 8;
  const int sxorV = (vr0 & 7) << 4;
  const int kswz  = (l31 & 7) << 4;

  bf16x8 stK[4], stV[4];
  #define LOAD_TILE(T)                                                              \
    do { int kt_ = (T) * 128;                                                       \
      _Pragma("unroll")                                                             \
      for (int i_ = 0; i_ < 4; ++i_)                                                \
        stK[i_] = *(const bf16x8*)(kp + (size_t)(kt_ + i_*32 + srowK) * 64 + scol8);\
      _Pragma("unroll")                                                             \
      for (int i_ = 0; i_ < 4; ++i_)                                                \
        stV[i_] = *(const bf16x8*)(vp + (size_t)(i_*16 + vr0) * 2048 + kt_ + vc8);  \
    } while (0)
  #define WRITE_TILE(P_)                                                            \
    do {                                                                            \
      _Pragma("unroll")                                                             \
      for (int i_ = 0; i_ < 4; ++i_)                                                \
        *(bf16x8*)((char*)Kl[P_] + (i_*32 + srowK) * 128 + (scolB ^ sxorK)) = stK[i_];\
      _Pragma("unroll")                                                             \
      for (int i_ = 0; i_ < 4; ++i_)                                                \
        *(bf16x8*)((char*)Vl[P_] + (i_*16 + vr0) * 256 + (vcB ^ sxorV)) = stV[i_];  \
    } while (0)

  bf16x8 bq[4];
  #pragma unroll
  for (int dj = 0; dj < 4; ++dj)
    bq[dj] = *(const bf16x8*)(Q + base + (size_t)(q0 + l31) * 64 + dj*16 + hi*8);

  const float Mh = fabsf(temp[h]) * 1.44269504088896f;
  f32x16 cinit;
  #pragma unroll
  for (int r = 0; r < 16; ++r) cinit[r] = -Mh;

  f32x16 o[2];
  #pragma unroll
  for (int td = 0; td < 2; ++td)
    #pragma unroll
    for (int r = 0; r < 16; ++r) o[td][r] = 0.f;
  float lp = 0.f;

  LOAD_TILE(0); WRITE_TILE(0);
  LOAD_TILE(1); WRITE_TILE(1);
  LOAD_TILE(2);
  __syncthreads();

  for (int t = 0; t < 16; ++t) {
    const int p = t & 1;
    const char* kl = (const char*)Kl[p];
    const char* vl = (const char*)Vl[p];

    f32x16 s[4];
    #pragma unroll
    for (int tk = 0; tk < 4; ++tk) {
      f32x16 z = cinit;
      #pragma unroll
      for (int dj = 0; dj < 4; ++dj) {
        bf16x8 ak = *(const bf16x8*)(kl + (tk*32 + l31) * 128 + ((dj*32 + hi*16) ^ kswz));
        z = __builtin_amdgcn_mfma_f32_32x32x16_bf16(ak, bq[dj], z, 0, 0, 0);
      }
      s[tk] = z;
    }
    #pragma unroll
    for (int tk = 0; tk < 4; ++tk)
      #pragma unroll
      for (int r = 0; r < 16; ++r) {
        float pv = __builtin_amdgcn_exp2f(s[tk][r]);
        s[tk][r] = pv;
        lp += pv;
      }
    bf16x8 pa[8];
    #pragma unroll
    for (int tk = 0; tk < 4; ++tk)
      #pragma unroll
      for (int j = 0; j < 2; ++j) {
        unsigned w0 = cvtpk(s[tk][8*j+0], s[tk][8*j+1]);
        unsigned w2 = cvtpk(s[tk][8*j+4], s[tk][8*j+5]);
        unsigned w1 = cvtpk(s[tk][8*j+2], s[tk][8*j+3]);
        unsigned w3 = cvtpk(s[tk][8*j+6], s[tk][8*j+7]);
        plswap(w0, w2);
        plswap(w1, w3);
        u32x4 pw = {w0, w1, w2, w3};
        pa[tk*2 + j] = __builtin_bit_cast(bf16x8, pw);
      }
    #pragma unroll
    for (int td = 0; td < 2; ++td) {
      f32x16 acc = o[td];
      #pragma unroll
      for (int kj = 0; kj < 8; ++kj) {
        bf16x8 bv = *(const bf16x8*)(vl + (td*32 + l31) * 256 + ((kj*32 + hi*16) ^ kswz));
        acc = __builtin_amdgcn_mfma_f32_32x32x16_bf16(pa[kj], bv, acc, 0, 0, 0);
      }
      o[td] = acc;
    }

    if (t < 15) {
      __syncthreads();
      if (t < 14) {
        WRITE_TILE(p);
        if (t < 13) LOAD_TILE(t + 3);
      }
    }
  }
  #undef LOAD_TILE
  #undef WRITE_TILE

  lp += __shfl_xor(lp, 32);
  if (hi == 0) Ls[w][l31] = 1.0f / lp;
  #pragma unroll
  for (int td = 0; td < 2; ++td)
    #pragma unroll
    for (int r = 0; r < 16; ++r) {
      int qr = (r & 3) + 8 * (r >> 2) + 4 * hi;
      float li = Ls[w][qr];
      int row = b * 2048 + q0 + qr;
      int col = h * 64 + td * 32 + l31;
      AO[(size_t)row * 512 + col] = f2bf(o[td][r] * li);
    }
}

extern "C" void kernel_launch(void* const* d_in, const int* in_sizes, int n_in,
                              void* d_out, int out_size, void* d_ws, size_t ws_size,
                              hipStream_t stream)
{
  const float* x     = (const float*)d_in[0];   // [4,2048,512] fp32
  const float* w_qkv = (const float*)d_in[1];   // [1536,512]  fp32
  const float* w_out = (const float*)d_in[2];   // [512,512]   fp32
  const float* temp  = (const float*)d_in[3];   // [8,1,1]     fp32
  float* out = (float*)d_out;
  short* ws  = (short*)d_ws;

  const size_t NQ = (size_t)4 * 8 * 2048 * 64;  // 4194304
  short* Qb   = ws;            // bf16 [b,h,n,64]
  short* Kb   = ws + NQ;       // bf16 [b,h,n,64]
  short* Vtb  = ws + 2 * NQ;   // bf16 [b,h,64,n]
  short* AO16 = ws + 3 * NQ;   // bf16 [8192,512] attention out (after attn)
  short* xb   = ws + 4 * NQ;   // bf16 x (live during gemm_qkv)
  short* wb   = AO16;          // bf16 w_qkv — dead before attn writes AO
  short* wob  = xb;            // bf16 w_out — cvt'd after gemm_qkv (xb dead)

  cvt_xw<<<dim3(2432), 256, 0, stream>>>(x, w_qkv, xb, wb);
  gemm_qkv<<<dim3(768), 256, 0, stream>>>(xb, wb, Qb, Kb, Vtb, temp);
  cvt_f32_bf16<<<dim3(128), 256, 0, stream>>>(w_out, wob, 32768);
  attn_fwd<<<dim3(32, 16), 256, 0, stream>>>(Qb, Kb, Vtb, AO16, temp);
  gemm_out<<<dim3(512), 256, 0, stream>>>(AO16, wob, out);
}